// Round 8
// baseline (352.611 us; speedup 1.0000x reference)
//
#include <hip/hip_runtime.h>

constexpr int NN = 50000;   // nodes
constexpr int NE = 800000;  // edges
constexpr int H  = 64;      // hidden
constexpr int NG = 64;      // graphs
constexpr int SLAB = 16;    // channels per conv pass (3.2 MB slab -> L2-resident)

constexpr int SCAN_B  = 1024;
constexpr int SCAN_NB = (NN + SCAN_B - 1) / SCAN_B;  // 49

// blocked feature layout: f[((c>>4)*NN + node)*16 + (c&15)]
__device__ __forceinline__ long long baddr(int node, int slab) {
    return ((long long)slab * NN + node) * SLAB;
}

// ---------------- zero degi ----------------
__global__ void k_zero(int* __restrict__ degi) {
    int i = blockIdx.x * blockDim.x + threadIdx.x;
    if (i < NN) degi[i] = 0;
}

// ---------------- CSR build (XCD-range partitioned) ----------------
constexpr int RB = 2048;  // total blocks (256 per range)

__global__ void k_degi(const int* __restrict__ dst, int* __restrict__ degi) {
    int range = blockIdx.x & 7;
    int lo = range * (NN / 8), hi = (range == 7) ? NN : lo + NN / 8;
    int stride = (gridDim.x >> 3) * blockDim.x;
    for (int e = (blockIdx.x >> 3) * blockDim.x + threadIdx.x; e < NE; e += stride) {
        int d = dst[e];
        if (d >= lo && d < hi) atomicAdd(&degi[d], 1);
    }
}

__global__ void k_scanA(const int* __restrict__ degi, int* __restrict__ rowptr,
                        int* __restrict__ bsum, float* __restrict__ sums,
                        float* __restrict__ cnt) {
    int tid = threadIdx.x, b = blockIdx.x;
    int zi = b * SCAN_B + tid;
    if (zi < NG * H) sums[zi] = 0.0f;
    else if (zi < NG * H + NG) cnt[zi - NG * H] = 0.0f;

    int i = b * SCAN_B + tid;
    int d = (i < NN) ? degi[i] : 0;
    int lane = tid & 63, w = tid >> 6;
    int v = d;
    for (int off = 1; off < 64; off <<= 1) {
        int u = __shfl_up(v, off);
        if (lane >= off) v += u;
    }
    __shared__ int wt[16], wo[16];
    if (lane == 63) wt[w] = v;
    __syncthreads();
    if (tid == 0) {
        int a = 0;
        for (int k = 0; k < 16; ++k) { wo[k] = a; a += wt[k]; }
        bsum[b] = a;
    }
    __syncthreads();
    if (i < NN) rowptr[i] = v - d + wo[w];
}

__global__ void k_scanB(int* __restrict__ bsum) {
    int lane = threadIdx.x;
    int v = (lane < SCAN_NB) ? bsum[lane] : 0;
    int s = v;
    for (int off = 1; off < 64; off <<= 1) {
        int u = __shfl_up(s, off);
        if (lane >= off) s += u;
    }
    if (lane < SCAN_NB) bsum[lane] = s - v;
}

__global__ void k_scanC(const int* __restrict__ bsum, int* __restrict__ rowptr,
                        const int* __restrict__ degi, float* __restrict__ dinv) {
    int i = blockIdx.x * SCAN_B + threadIdx.x;
    if (i < NN) {
        rowptr[i] += bsum[blockIdx.x];
        dinv[i] = rsqrtf((float)(degi[i] + 1));  // +1 self-loop
    }
}

// fill via pos = atomicAdd(&rowptr[d],1); post-fill rowptr[d] == segment end.
__global__ void k_fill(const int* __restrict__ src, const int* __restrict__ dst,
                       int* __restrict__ rowptr, int* __restrict__ csr_src) {
    int range = blockIdx.x & 7;
    int lo = range * (NN / 8), hi = (range == 7) ? NN : lo + NN / 8;
    int stride = (gridDim.x >> 3) * blockDim.x;
    for (int e = (blockIdx.x >> 3) * blockDim.x + threadIdx.x; e < NE; e += stride) {
        int d = dst[e];
        if (d >= lo && d < hi) {
            int pos = atomicAdd(&rowptr[d], 1);
            csr_src[pos] = src[e];
        }
    }
}

// ---------------- conv1 fused: hA = (A_hat * X) @ W1 + b1  (blocked output) ----
// wave per dst node. Phase 1: aggregate y[4] (lane c=lane&3, 16 edge slots).
// Phase 2: lane = output channel; y broadcast via shfl; W1 read direct (L2).
__global__ void k_conv1(const float* __restrict__ X, const int* __restrict__ rowptr,
                        const int* __restrict__ csr_src, const float* __restrict__ dinv,
                        const float* __restrict__ W1, const float* __restrict__ b1,
                        float* __restrict__ out) {
    int wid = (blockIdx.x * blockDim.x + threadIdx.x) >> 6;
    int lane = threadIdx.x & 63;
    int c = lane & 3, g = lane >> 2;
    if (wid >= NN) return;
    int beg = (wid > 0) ? rowptr[wid - 1] : 0;
    int end = rowptr[wid];
    float acc = 0.0f;
    for (int base = beg; base < end; base += 64) {
        int k = base + lane;
        int s = 0; float w = 0.0f;
        if (k < end) { s = csr_src[k]; w = dinv[s]; }
        int n = end - base; if (n > 64) n = 64;
        int iters = (n + 15) >> 4;
        for (int m = 0; m < iters; ++m) {
            int j = 16 * m + g;
            int ss = __shfl(s, j);
            float ww = __shfl(w, j);
            acc = fmaf(X[(long long)ss * 4 + c], ww, acc);
        }
    }
    acc += __shfl_xor(acc, 4);
    acc += __shfl_xor(acc, 8);
    acc += __shfl_xor(acc, 16);
    acc += __shfl_xor(acc, 32);
    float dd = dinv[wid];
    float y = dd * (acc + X[(long long)wid * 4 + c] * dd);  // lane's channel c
    float y0 = __shfl(y, 0), y1 = __shfl(y, 1), y2 = __shfl(y, 2), y3 = __shfl(y, 3);
    float o = b1[lane];
    o = fmaf(y0, W1[0 * H + lane], o);
    o = fmaf(y1, W1[1 * H + lane], o);
    o = fmaf(y2, W1[2 * H + lane], o);
    o = fmaf(y3, W1[3 * H + lane], o);
    out[baddr(wid, lane >> 4) + (lane & 15)] = o;
}

// ---------------- dense per-node GEMM: t = relu(h) @ W  (blocked in/out) ------
// block = 256 threads; each thread: 4 rows x 4 channels.
__global__ void k_gemm(const float* __restrict__ h, const float* __restrict__ W,
                       float* __restrict__ t) {
    __shared__ float4 Wl[H][16];
    int tid = threadIdx.x;
    {
        const float4* W4 = (const float4*)W;
        for (int i = tid; i < H * 16; i += 256) ((float4*)Wl)[i] = W4[i];
    }
    __syncthreads();
    int cg = tid & 15;
    int rg = tid >> 4;
    int row0 = blockIdx.x * 64 + rg * 4;

    float4 acc[4];
#pragma unroll
    for (int i = 0; i < 4; ++i) acc[i] = make_float4(0.f, 0.f, 0.f, 0.f);

#pragma unroll
    for (int k4 = 0; k4 < H / 4; ++k4) {
        float4 w0 = Wl[4 * k4 + 0][cg];
        float4 w1 = Wl[4 * k4 + 1][cg];
        float4 w2 = Wl[4 * k4 + 2][cg];
        float4 w3 = Wl[4 * k4 + 3][cg];
        long long sb = (long long)(k4 >> 2) * NN * SLAB + (k4 & 3) * 4;
#pragma unroll
        for (int i = 0; i < 4; ++i) {
            int r = row0 + i;
            if (r >= NN) break;
            float4 hv = *(const float4*)(h + sb + (long long)r * SLAB);
            hv.x = fmaxf(hv.x, 0.f); hv.y = fmaxf(hv.y, 0.f);
            hv.z = fmaxf(hv.z, 0.f); hv.w = fmaxf(hv.w, 0.f);
            acc[i].x = fmaf(hv.x, w0.x, acc[i].x);
            acc[i].y = fmaf(hv.x, w0.y, acc[i].y);
            acc[i].z = fmaf(hv.x, w0.z, acc[i].z);
            acc[i].w = fmaf(hv.x, w0.w, acc[i].w);
            acc[i].x = fmaf(hv.y, w1.x, acc[i].x);
            acc[i].y = fmaf(hv.y, w1.y, acc[i].y);
            acc[i].z = fmaf(hv.y, w1.z, acc[i].z);
            acc[i].w = fmaf(hv.y, w1.w, acc[i].w);
            acc[i].x = fmaf(hv.z, w2.x, acc[i].x);
            acc[i].y = fmaf(hv.z, w2.y, acc[i].y);
            acc[i].z = fmaf(hv.z, w2.z, acc[i].z);
            acc[i].w = fmaf(hv.z, w2.w, acc[i].w);
            acc[i].x = fmaf(hv.w, w3.x, acc[i].x);
            acc[i].y = fmaf(hv.w, w3.y, acc[i].y);
            acc[i].z = fmaf(hv.w, w3.z, acc[i].z);
            acc[i].w = fmaf(hv.w, w3.w, acc[i].w);
        }
    }
    long long ob = (long long)(cg >> 2) * NN * SLAB + (cg & 3) * 4;
#pragma unroll
    for (int i = 0; i < 4; ++i) {
        int r = row0 + i;
        if (r < NN) *(float4*)(t + ob + (long long)r * SLAB) = acc[i];
    }
}

// ---------------- pull conv pass: 16 channels (slab p L2-resident) -----------
// out[d,16p:16p+16] = b[..] + dinv[d]*( sum_s t_p[s]*dinv[s] + t_p[d]*dinv[d] )
// wave = 1 dst; lane = (g = lane>>2 edge slot of 16, q = lane&3 float4 slot)
__global__ void k_conv16(const float* __restrict__ t, const int* __restrict__ rowptr,
                         const int* __restrict__ csr_src, const float* __restrict__ dinv,
                         const float* __restrict__ b, float* __restrict__ out, int p) {
    int wid = (blockIdx.x * blockDim.x + threadIdx.x) >> 6;
    int lane = threadIdx.x & 63;
    int q = lane & 3, g = lane >> 2;
    if (wid >= NN) return;
    const float* tp = t + (long long)p * NN * SLAB;
    float ax = 0.f, ay = 0.f, az = 0.f, aw = 0.f;
    int beg = (wid > 0) ? rowptr[wid - 1] : 0;
    int end = rowptr[wid];
    for (int base = beg; base < end; base += 64) {
        int k = base + lane;
        int s = 0; float w = 0.0f;
        if (k < end) { s = csr_src[k]; w = dinv[s]; }
        int n = end - base; if (n > 64) n = 64;
        int iters = (n + 15) >> 4;
        for (int m = 0; m < iters; ++m) {
            int j = 16 * m + g;
            int ss = __shfl(s, j);
            float ww = __shfl(w, j);
            const float4 v = *(const float4*)(tp + (long long)ss * SLAB + 4 * q);
            ax = fmaf(v.x, ww, ax); ay = fmaf(v.y, ww, ay);
            az = fmaf(v.z, ww, az); aw = fmaf(v.w, ww, aw);
        }
    }
    // reduce over edge-slot bits (lane bits 2..5)
    ax += __shfl_xor(ax, 4); ax += __shfl_xor(ax, 8);
    ax += __shfl_xor(ax, 16); ax += __shfl_xor(ax, 32);
    ay += __shfl_xor(ay, 4); ay += __shfl_xor(ay, 8);
    ay += __shfl_xor(ay, 16); ay += __shfl_xor(ay, 32);
    az += __shfl_xor(az, 4); az += __shfl_xor(az, 8);
    az += __shfl_xor(az, 16); az += __shfl_xor(az, 32);
    aw += __shfl_xor(aw, 4); aw += __shfl_xor(aw, 8);
    aw += __shfl_xor(aw, 16); aw += __shfl_xor(aw, 32);
    if (g == 0) {
        float dd = dinv[wid];
        const float4 sv = *(const float4*)(tp + (long long)wid * SLAB + 4 * q);
        const float4 bv = *(const float4*)(b + p * SLAB + 4 * q);
        float4 o;
        o.x = bv.x + dd * (ax + sv.x * dd);
        o.y = bv.y + dd * (ay + sv.y * dd);
        o.z = bv.z + dd * (az + sv.z * dd);
        o.w = bv.w + dd * (aw + sv.w * dd);
        *(float4*)(out + (long long)p * NN * SLAB + (long long)wid * SLAB + 4 * q) = o;
    }
}

// ---------------- pooling (batch sorted; blocked input) ----------------
constexpr int POOL_WAVES = 512;
constexpr int POOL_STRIP = (NN + POOL_WAVES - 1) / POOL_WAVES;  // 98

__global__ void k_pool(const float* __restrict__ h, const int* __restrict__ batch,
                       float* __restrict__ sums, float* __restrict__ cnt) {
    int wid = (blockIdx.x * blockDim.x + threadIdx.x) >> 6;
    int c = threadIdx.x & 63;
    int beg = wid * POOL_STRIP, end = min(NN, beg + POOL_STRIP);
    if (beg >= end) return;
    long long sb = (long long)(c >> 4) * NN * SLAB + (c & 15);
    int curg = batch[beg];
    float acc = 0.0f; int run = 0;
    for (int r = beg; r < end; ++r) {
        int g = batch[r];
        if (g != curg) {
            atomicAdd(&sums[curg * H + c], acc);
            if (c == 0) atomicAdd(&cnt[curg], (float)run);
            curg = g; acc = 0.0f; run = 0;
        }
        acc += h[sb + (long long)r * SLAB];
        ++run;
    }
    atomicAdd(&sums[curg * H + c], acc);
    if (c == 0) atomicAdd(&cnt[curg], (float)run);
}

// ---------------- head ----------------
__global__ void k_head(const float* __restrict__ sums, const float* __restrict__ cnt,
                       const float* __restrict__ Wpre, const float* __restrict__ bpre,
                       const float* __restrict__ Wlin, const float* __restrict__ blin,
                       float* __restrict__ out) {
    __shared__ float g[NG * H];
    __shared__ float p[NG * 32];
    int tid = threadIdx.x;
    for (int i = tid; i < NG * H; i += blockDim.x) {
        int gi = i >> 6;
        g[i] = sums[i] / fmaxf(cnt[gi], 1.0f);
    }
    __syncthreads();
    for (int i = tid; i < NG * 32; i += blockDim.x) {
        int gi = i >> 5, j = i & 31;
        float acc = bpre[j];
        for (int k = 0; k < H; ++k) acc = fmaf(g[gi * H + k], Wpre[k * 32 + j], acc);
        p[i] = acc;
    }
    __syncthreads();
    for (int i = tid; i < NG * 4; i += blockDim.x) {
        int gi = i >> 2, o = i & 3;
        float acc = blin[o];
        for (int j = 0; j < 32; ++j) acc = fmaf(p[gi * 32 + j], Wlin[j * 4 + o], acc);
        out[i] = acc;
    }
}

extern "C" void kernel_launch(void* const* d_in, const int* in_sizes, int n_in,
                              void* d_out, int out_size, void* d_ws, size_t ws_size,
                              hipStream_t stream) {
    const float* x     = (const float*)d_in[0];
    const int*   ei    = (const int*)d_in[1];
    const int*   batch = (const int*)d_in[2];
    const float* W1    = (const float*)d_in[3];
    const float* b1    = (const float*)d_in[4];
    const float* W2    = (const float*)d_in[5];
    const float* b2    = (const float*)d_in[6];
    const float* W3    = (const float*)d_in[7];
    const float* b3    = (const float*)d_in[8];
    const float* Wpre  = (const float*)d_in[9];
    const float* bpre  = (const float*)d_in[10];
    const float* Wlin  = (const float*)d_in[11];
    const float* blin  = (const float*)d_in[12];
    float* out = (float*)d_out;

    const int* src = ei;
    const int* dst = ei + NE;

    // workspace layout
    int*   degi   = (int*)d_ws;            // NN
    float* sums   = (float*)(degi + NN);   // NG*H
    float* cnt    = sums + NG * H;         // NG
    int*   bsum   = (int*)(cnt + NG);      // SCAN_NB
    int*   rowptr = bsum + SCAN_NB;        // NN
    int*   csr_s  = rowptr + NN;           // NE
    float* dinv   = (float*)(csr_s + NE);  // NN
    float* tbuf   = dinv + NN;             // NN*H (4 blocked slabs)
    float* hA     = tbuf + (long long)NN * H;
    float* hB     = hA + (long long)NN * H;

    const int B = 256;
    const int gNH = (NN * H + B - 1) / B;     // one wave per node
    const int gG  = (NN + 63) / 64;           // gemm: 64 rows per block

    k_zero<<<(NN + B - 1) / B, B, 0, stream>>>(degi);

    // CSR + norm (XCD-range partitioned build)
    k_degi<<<RB, B, 0, stream>>>(dst, degi);
    k_scanA<<<SCAN_NB, SCAN_B, 0, stream>>>(degi, rowptr, bsum, sums, cnt);
    k_scanB<<<1, 64, 0, stream>>>(bsum);
    k_scanC<<<SCAN_NB, SCAN_B, 0, stream>>>(bsum, rowptr, degi, dinv);
    k_fill<<<RB, B, 0, stream>>>(src, dst, rowptr, csr_s);

    // conv1 fused: hA = (A_hat X) W1 + b1   (blocked)
    k_conv1<<<gNH, B, 0, stream>>>(x, rowptr, csr_s, dinv, W1, b1, hA);

    // conv2: tbuf = relu(hA) @ W2 (blocked), then 4 L2-resident passes
    k_gemm<<<gG, B, 0, stream>>>(hA, W2, tbuf);
    for (int p = 0; p < 4; ++p)
        k_conv16<<<gNH, B, 0, stream>>>(tbuf, rowptr, csr_s, dinv, b2, hB, p);

    // conv3
    k_gemm<<<gG, B, 0, stream>>>(hB, W3, tbuf);
    for (int p = 0; p < 4; ++p)
        k_conv16<<<gNH, B, 0, stream>>>(tbuf, rowptr, csr_s, dinv, b3, hA, p);

    // pool + head
    k_pool<<<POOL_WAVES / 4, B, 0, stream>>>(hA, batch, sums, cnt);
    k_head<<<1, B, 0, stream>>>(sums, cnt, Wpre, bpre, Wlin, blin, out);
}

// Round 9
// 296.349 us; speedup vs baseline: 1.1899x; 1.1899x over previous
//
#include <hip/hip_runtime.h>

constexpr int NN = 50000;   // nodes
constexpr int NE = 800000;  // edges
constexpr int H  = 64;      // hidden
constexpr int NG = 64;      // graphs

constexpr int SCAN_B  = 1024;
constexpr int SCAN_NB = (NN + SCAN_B - 1) / SCAN_B;  // 49
constexpr int RB = 2048;    // range-partitioned edge kernels: 256 blocks/range

// ---------------- zero degi ----------------
__global__ void k_zero(int* __restrict__ degi) {
    int i = blockIdx.x * blockDim.x + threadIdx.x;
    if (i < NN) degi[i] = 0;
}

// ---------------- CSR build (XCD-range partitioned) ----------------
__global__ void k_degi(const int* __restrict__ dst, int* __restrict__ degi) {
    int range = blockIdx.x & 7;
    int lo = range * (NN / 8), hi = (range == 7) ? NN : lo + NN / 8;
    int stride = (gridDim.x >> 3) * blockDim.x;
    for (int e = (blockIdx.x >> 3) * blockDim.x + threadIdx.x; e < NE; e += stride) {
        int d = dst[e];
        if (d >= lo && d < hi) atomicAdd(&degi[d], 1);
    }
}

// per-block local exclusive scan; bsum[b] = block total; also zeros sums
__global__ void k_scanA(const int* __restrict__ degi, int* __restrict__ rowptr,
                        int* __restrict__ bsum, float* __restrict__ sums) {
    int tid = threadIdx.x, b = blockIdx.x;
    int zi = b * SCAN_B + tid;
    if (zi < NG * H) sums[zi] = 0.0f;

    int i = b * SCAN_B + tid;
    int d = (i < NN) ? degi[i] : 0;
    int lane = tid & 63, w = tid >> 6;
    int v = d;
    for (int off = 1; off < 64; off <<= 1) {
        int u = __shfl_up(v, off);
        if (lane >= off) v += u;
    }
    __shared__ int wt[16], wo[16];
    if (lane == 63) wt[w] = v;
    __syncthreads();
    if (tid == 0) {
        int a = 0;
        for (int k = 0; k < 16; ++k) { wo[k] = a; a += wt[k]; }
        bsum[b] = a;
    }
    __syncthreads();
    if (i < NN) rowptr[i] = v - d + wo[w];
}

// merged scanB+scanC: every block redundantly wave-scans bsum[49], adds its
// offset, and computes dinv.
__global__ void k_scanC2(const int* __restrict__ bsum, int* __restrict__ rowptr,
                         const int* __restrict__ degi, float* __restrict__ dinv) {
    __shared__ int boff;
    int tid = threadIdx.x;
    if (tid < 64) {
        int v = (tid < SCAN_NB) ? bsum[tid] : 0;
        int s = v;
        for (int off = 1; off < 64; off <<= 1) {
            int u = __shfl_up(s, off);
            if (tid >= off) s += u;
        }
        if (tid == (int)blockIdx.x) boff = s - v;  // exclusive prefix for this block
    }
    __syncthreads();
    int i = blockIdx.x * SCAN_B + tid;
    if (i < NN) {
        rowptr[i] += boff;
        dinv[i] = rsqrtf((float)(degi[i] + 1));  // +1 self-loop
    }
}

// fill via pos = atomicAdd(&rowptr[d],1); post-fill rowptr[d] == segment end.
__global__ void k_fill(const int* __restrict__ src, const int* __restrict__ dst,
                       int* __restrict__ rowptr, int* __restrict__ csr_src) {
    int range = blockIdx.x & 7;
    int lo = range * (NN / 8), hi = (range == 7) ? NN : lo + NN / 8;
    int stride = (gridDim.x >> 3) * blockDim.x;
    for (int e = (blockIdx.x >> 3) * blockDim.x + threadIdx.x; e < NE; e += stride) {
        int d = dst[e];
        if (d >= lo && d < hi) {
            int pos = atomicAdd(&rowptr[d], 1);
            csr_src[pos] = src[e];
        }
    }
}

// ---------------- conv1 fused: hA = (A_hat * X) @ W1 + b1 (row-major) --------
__global__ void k_conv1(const float* __restrict__ X, const int* __restrict__ rowptr,
                        const int* __restrict__ csr_src, const float* __restrict__ dinv,
                        const float* __restrict__ W1, const float* __restrict__ b1,
                        float* __restrict__ out) {
    int wid = (blockIdx.x * blockDim.x + threadIdx.x) >> 6;
    int lane = threadIdx.x & 63;
    int c = lane & 3, g = lane >> 2;
    if (wid >= NN) return;
    int beg = (wid > 0) ? rowptr[wid - 1] : 0;
    int end = rowptr[wid];
    float acc = 0.0f;
    for (int base = beg; base < end; base += 64) {
        int k = base + lane;
        int s = 0; float w = 0.0f;
        if (k < end) { s = csr_src[k]; w = dinv[s]; }
        int n = end - base; if (n > 64) n = 64;
        int iters = (n + 15) >> 4;
        for (int m = 0; m < iters; ++m) {
            int j = 16 * m + g;
            int ss = __shfl(s, j);
            float ww = __shfl(w, j);
            acc = fmaf(X[(long long)ss * 4 + c], ww, acc);
        }
    }
    acc += __shfl_xor(acc, 4);
    acc += __shfl_xor(acc, 8);
    acc += __shfl_xor(acc, 16);
    acc += __shfl_xor(acc, 32);
    float dd = dinv[wid];
    float y = dd * (acc + X[(long long)wid * 4 + c] * dd);  // lane's channel c of y
    float y0 = __shfl(y, 0), y1 = __shfl(y, 1), y2 = __shfl(y, 2), y3 = __shfl(y, 3);
    float o = b1[lane];
    o = fmaf(y0, W1[0 * H + lane], o);
    o = fmaf(y1, W1[1 * H + lane], o);
    o = fmaf(y2, W1[2 * H + lane], o);
    o = fmaf(y3, W1[3 * H + lane], o);
    out[(long long)wid * H + lane] = o;
}

// ---------------- dense per-node GEMM: t = relu(h) @ W (row-major) -----------
__global__ void k_gemm(const float* __restrict__ h, const float* __restrict__ W,
                       float* __restrict__ t) {
    __shared__ float4 Wl[H][16];
    int tid = threadIdx.x;
    {
        const float4* W4 = (const float4*)W;
        for (int i = tid; i < H * 16; i += 256) ((float4*)Wl)[i] = W4[i];
    }
    __syncthreads();
    int cg = tid & 15;
    int rg = tid >> 4;
    int row0 = blockIdx.x * 64 + rg * 4;

    float4 acc[4];
#pragma unroll
    for (int i = 0; i < 4; ++i) acc[i] = make_float4(0.f, 0.f, 0.f, 0.f);

    const float4* h4 = (const float4*)h;
#pragma unroll
    for (int k4 = 0; k4 < H / 4; ++k4) {
        float4 w0 = Wl[4 * k4 + 0][cg];
        float4 w1 = Wl[4 * k4 + 1][cg];
        float4 w2 = Wl[4 * k4 + 2][cg];
        float4 w3 = Wl[4 * k4 + 3][cg];
#pragma unroll
        for (int i = 0; i < 4; ++i) {
            int r = row0 + i;
            if (r >= NN) break;
            float4 hv = h4[(long long)r * (H / 4) + k4];
            hv.x = fmaxf(hv.x, 0.f); hv.y = fmaxf(hv.y, 0.f);
            hv.z = fmaxf(hv.z, 0.f); hv.w = fmaxf(hv.w, 0.f);
            acc[i].x = fmaf(hv.x, w0.x, acc[i].x);
            acc[i].y = fmaf(hv.x, w0.y, acc[i].y);
            acc[i].z = fmaf(hv.x, w0.z, acc[i].z);
            acc[i].w = fmaf(hv.x, w0.w, acc[i].w);
            acc[i].x = fmaf(hv.y, w1.x, acc[i].x);
            acc[i].y = fmaf(hv.y, w1.y, acc[i].y);
            acc[i].z = fmaf(hv.y, w1.z, acc[i].z);
            acc[i].w = fmaf(hv.y, w1.w, acc[i].w);
            acc[i].x = fmaf(hv.z, w2.x, acc[i].x);
            acc[i].y = fmaf(hv.z, w2.y, acc[i].y);
            acc[i].z = fmaf(hv.z, w2.z, acc[i].z);
            acc[i].w = fmaf(hv.z, w2.w, acc[i].w);
            acc[i].x = fmaf(hv.w, w3.x, acc[i].x);
            acc[i].y = fmaf(hv.w, w3.y, acc[i].y);
            acc[i].z = fmaf(hv.w, w3.z, acc[i].z);
            acc[i].w = fmaf(hv.w, w3.w, acc[i].w);
        }
    }
#pragma unroll
    for (int i = 0; i < 4; ++i) {
        int r = row0 + i;
        if (r < NN) *(float4*)(t + (long long)r * H + 4 * cg) = acc[i];
    }
}

// ---------------- pull conv (H=64), 4-deep pipelined gathers -----------------
__global__ void k_conv(const float* __restrict__ t, const int* __restrict__ rowptr,
                       const int* __restrict__ csr_src, const float* __restrict__ dinv,
                       const float* __restrict__ b, float* __restrict__ out) {
    int wid = (blockIdx.x * blockDim.x + threadIdx.x) >> 6;
    int lane = threadIdx.x & 63;
    int l = lane & 15, g = lane >> 4;
    if (wid >= NN) return;
    float ax = 0.0f, ay = 0.0f, az = 0.0f, aw = 0.0f;
    int beg = (wid > 0) ? rowptr[wid - 1] : 0;
    int end = rowptr[wid];
    for (int base = beg; base < end; base += 64) {
        int k = base + lane;
        int s = 0; float w = 0.0f;
        if (k < end) { s = csr_src[k]; w = dinv[s]; }
        int n = end - base; if (n > 64) n = 64;
        int rounds = (n + 15) >> 4;
        for (int m = 0; m < rounds; ++m) {
            int j0 = 16 * m + g;
            int ss0 = __shfl(s, j0);      float ww0 = __shfl(w, j0);
            int ss1 = __shfl(s, j0 + 4);  float ww1 = __shfl(w, j0 + 4);
            int ss2 = __shfl(s, j0 + 8);  float ww2 = __shfl(w, j0 + 8);
            int ss3 = __shfl(s, j0 + 12); float ww3 = __shfl(w, j0 + 12);
            const float4 v0 = *(const float4*)(t + (long long)ss0 * H + 4 * l);
            const float4 v1 = *(const float4*)(t + (long long)ss1 * H + 4 * l);
            const float4 v2 = *(const float4*)(t + (long long)ss2 * H + 4 * l);
            const float4 v3 = *(const float4*)(t + (long long)ss3 * H + 4 * l);
            ax = fmaf(v0.x, ww0, ax); ay = fmaf(v0.y, ww0, ay);
            az = fmaf(v0.z, ww0, az); aw = fmaf(v0.w, ww0, aw);
            ax = fmaf(v1.x, ww1, ax); ay = fmaf(v1.y, ww1, ay);
            az = fmaf(v1.z, ww1, az); aw = fmaf(v1.w, ww1, aw);
            ax = fmaf(v2.x, ww2, ax); ay = fmaf(v2.y, ww2, ay);
            az = fmaf(v2.z, ww2, az); aw = fmaf(v2.w, ww2, aw);
            ax = fmaf(v3.x, ww3, ax); ay = fmaf(v3.y, ww3, ay);
            az = fmaf(v3.z, ww3, az); aw = fmaf(v3.w, ww3, aw);
        }
    }
    ax += __shfl_xor(ax, 16); ax += __shfl_xor(ax, 32);
    ay += __shfl_xor(ay, 16); ay += __shfl_xor(ay, 32);
    az += __shfl_xor(az, 16); az += __shfl_xor(az, 32);
    aw += __shfl_xor(aw, 16); aw += __shfl_xor(aw, 32);
    if (g == 0) {
        float dd = dinv[wid];
        const float4 sv = *(const float4*)(t + (long long)wid * H + 4 * l);
        const float4 bv = *(const float4*)(b + 4 * l);
        float4 o;
        o.x = bv.x + dd * (ax + sv.x * dd);
        o.y = bv.y + dd * (ay + sv.y * dd);
        o.z = bv.z + dd * (az + sv.z * dd);
        o.w = bv.w + dd * (aw + sv.w * dd);
        *(float4*)(out + (long long)wid * H + 4 * l) = o;
    }
}

// ---------------- pooled-adjacency matrix M [NN][NG] -------------------------
// M[s][g] = sum_{edges s->d, batch[d]=g} dinv[s]*dinv[d] + [batch[s]=g]*dinv[s]^2
// init: zero row + self term (no atomics needed)
__global__ void k_minit(const int* __restrict__ batch, const float* __restrict__ dinv,
                        float* __restrict__ M) {
    int idx = blockIdx.x * blockDim.x + threadIdx.x;  // node*16 + q
    if (idx >= NN * 16) return;
    int node = idx >> 4, q = idx & 15;
    int g = batch[node];
    float dd = dinv[node];
    float vals[4] = {0.f, 0.f, 0.f, 0.f};
    if ((g >> 2) == q) vals[g & 3] = dd * dd;
    *(float4*)(M + (long long)node * NG + 4 * q) =
        make_float4(vals[0], vals[1], vals[2], vals[3]);
}

// edge accumulate, range-partitioned on SRC (write window 1.6 MB -> L2-local)
__global__ void k_mbuild(const int* __restrict__ src, const int* __restrict__ dst,
                         const int* __restrict__ batch, const float* __restrict__ dinv,
                         float* __restrict__ M) {
    int range = blockIdx.x & 7;
    int lo = range * (NN / 8), hi = (range == 7) ? NN : lo + NN / 8;
    int stride = (gridDim.x >> 3) * blockDim.x;
    for (int e = (blockIdx.x >> 3) * blockDim.x + threadIdx.x; e < NE; e += stride) {
        int s = src[e];
        if (s >= lo && s < hi) {
            int d = dst[e];
            atomicAdd(&M[(long long)s * NG + batch[d]], dinv[s] * dinv[d]);
        }
    }
}

// sums[g][c] = sum_s M[s][g] * t[s][c]   (streaming outer-product GEMM)
constexpr int MG_BLOCKS = 256;
__global__ void k_mgemm(const float* __restrict__ t, const float* __restrict__ M,
                        float* __restrict__ sums) {
    __shared__ float ts[8][64], ms[8][64];
    int tid = threadIdx.x;
    int cg = tid & 15, gg = tid >> 4;
    float acc[4][4] = {};
    int chunk = (NN + MG_BLOCKS - 1) / MG_BLOCKS;  // 196
    int beg = blockIdx.x * chunk, end = min(NN, beg + chunk);
    for (int n0 = beg; n0 < end; n0 += 8) {
        {
            int half = tid >> 7;       // 0: ts, 1: ms
            int lt = tid & 127;        // 128 loaders each, 8 nodes x 16 float4
            int node = n0 + (lt >> 4), q = lt & 15;
            float4 v = make_float4(0.f, 0.f, 0.f, 0.f);
            if (node < end) {
                const float* sp = half ? M : t;
                v = *(const float4*)(sp + (long long)node * 64 + 4 * q);
            }
            float* dp = half ? &ms[0][0] : &ts[0][0];
            *(float4*)(dp + (lt >> 4) * 64 + 4 * q) = v;
        }
        __syncthreads();
#pragma unroll
        for (int n = 0; n < 8; ++n) {
            float4 tv = *(float4*)(&ts[n][4 * cg]);
            float4 mv = *(float4*)(&ms[n][4 * gg]);
            acc[0][0] = fmaf(mv.x, tv.x, acc[0][0]);
            acc[0][1] = fmaf(mv.x, tv.y, acc[0][1]);
            acc[0][2] = fmaf(mv.x, tv.z, acc[0][2]);
            acc[0][3] = fmaf(mv.x, tv.w, acc[0][3]);
            acc[1][0] = fmaf(mv.y, tv.x, acc[1][0]);
            acc[1][1] = fmaf(mv.y, tv.y, acc[1][1]);
            acc[1][2] = fmaf(mv.y, tv.z, acc[1][2]);
            acc[1][3] = fmaf(mv.y, tv.w, acc[1][3]);
            acc[2][0] = fmaf(mv.z, tv.x, acc[2][0]);
            acc[2][1] = fmaf(mv.z, tv.y, acc[2][1]);
            acc[2][2] = fmaf(mv.z, tv.z, acc[2][2]);
            acc[2][3] = fmaf(mv.z, tv.w, acc[2][3]);
            acc[3][0] = fmaf(mv.w, tv.x, acc[3][0]);
            acc[3][1] = fmaf(mv.w, tv.y, acc[3][1]);
            acc[3][2] = fmaf(mv.w, tv.z, acc[3][2]);
            acc[3][3] = fmaf(mv.w, tv.w, acc[3][3]);
        }
        __syncthreads();
    }
#pragma unroll
    for (int i = 0; i < 4; ++i)
#pragma unroll
        for (int j = 0; j < 4; ++j)
            atomicAdd(&sums[(4 * gg + i) * 64 + 4 * cg + j], acc[i][j]);
}

// ---------------- head: mean = b3 + sums/cnt; two tiny MLPs ------------------
__global__ void k_head2(const float* __restrict__ sums, const int* __restrict__ batch,
                        const float* __restrict__ b3,
                        const float* __restrict__ Wpre, const float* __restrict__ bpre,
                        const float* __restrict__ Wlin, const float* __restrict__ blin,
                        float* __restrict__ out) {
    __shared__ float g[NG * H];
    __shared__ float p[NG * 32];
    __shared__ float cl[NG];
    int tid = threadIdx.x;
    if (tid < NG) {
        int gq = tid;
        int lo = 0, hi = NN;
        while (lo < hi) { int m = (lo + hi) >> 1; if (batch[m] < gq) lo = m + 1; else hi = m; }
        int L = lo;
        lo = 0; hi = NN;
        while (lo < hi) { int m = (lo + hi) >> 1; if (batch[m] <= gq) lo = m + 1; else hi = m; }
        cl[tid] = fmaxf((float)(lo - L), 1.0f);
    }
    __syncthreads();
    for (int i = tid; i < NG * H; i += blockDim.x) {
        int gi = i >> 6, c = i & 63;
        g[i] = b3[c] + sums[i] / cl[gi];
    }
    __syncthreads();
    for (int i = tid; i < NG * 32; i += blockDim.x) {
        int gi = i >> 5, j = i & 31;
        float acc = bpre[j];
        for (int k = 0; k < H; ++k) acc = fmaf(g[gi * H + k], Wpre[k * 32 + j], acc);
        p[i] = acc;
    }
    __syncthreads();
    for (int i = tid; i < NG * 4; i += blockDim.x) {
        int gi = i >> 2, o = i & 3;
        float acc = blin[o];
        for (int j = 0; j < 32; ++j) acc = fmaf(p[gi * 32 + j], Wlin[j * 4 + o], acc);
        out[i] = acc;
    }
}

extern "C" void kernel_launch(void* const* d_in, const int* in_sizes, int n_in,
                              void* d_out, int out_size, void* d_ws, size_t ws_size,
                              hipStream_t stream) {
    const float* x     = (const float*)d_in[0];
    const int*   ei    = (const int*)d_in[1];
    const int*   batch = (const int*)d_in[2];
    const float* W1    = (const float*)d_in[3];
    const float* b1    = (const float*)d_in[4];
    const float* W2    = (const float*)d_in[5];
    const float* b2    = (const float*)d_in[6];
    const float* W3    = (const float*)d_in[7];
    const float* b3    = (const float*)d_in[8];
    const float* Wpre  = (const float*)d_in[9];
    const float* bpre  = (const float*)d_in[10];
    const float* Wlin  = (const float*)d_in[11];
    const float* blin  = (const float*)d_in[12];
    float* out = (float*)d_out;

    const int* src = ei;
    const int* dst = ei + NE;

    // workspace layout
    int*   degi   = (int*)d_ws;            // NN
    float* sums   = (float*)(degi + NN);   // NG*H
    int*   bsum   = (int*)(sums + NG * H); // SCAN_NB
    int*   rowptr = bsum + SCAN_NB;        // NN
    int*   csr_s  = rowptr + NN;           // NE
    float* dinv   = (float*)(csr_s + NE);  // NN
    float* Mm     = dinv + NN;             // NN*NG
    float* tbuf   = Mm + (long long)NN * NG;   // NN*H
    float* hA     = tbuf + (long long)NN * H;  // NN*H
    float* hB     = hA + (long long)NN * H;    // NN*H

    const int B = 256;
    const int gNH = (NN * H + B - 1) / B;     // one wave per node
    const int gG  = (NN + 63) / 64;           // gemm: 64 rows per block

    k_zero<<<(NN + B - 1) / B, B, 0, stream>>>(degi);

    // CSR + norm (XCD-range partitioned build)
    k_degi<<<RB, B, 0, stream>>>(dst, degi);
    k_scanA<<<SCAN_NB, SCAN_B, 0, stream>>>(degi, rowptr, bsum, sums);
    k_scanC2<<<SCAN_NB, SCAN_B, 0, stream>>>(bsum, rowptr, degi, dinv);
    k_fill<<<RB, B, 0, stream>>>(src, dst, rowptr, csr_s);

    // pooled-adjacency M (needs only dinv + batch)
    k_minit<<<(NN * 16 + B - 1) / B, B, 0, stream>>>(batch, dinv, Mm);
    k_mbuild<<<RB, B, 0, stream>>>(src, dst, batch, dinv, Mm);

    // conv1 fused: hA = (A_hat X) W1 + b1
    k_conv1<<<gNH, B, 0, stream>>>(x, rowptr, csr_s, dinv, W1, b1, hA);

    // conv2: tbuf = relu(hA) @ W2, then pull conv
    k_gemm<<<gG, B, 0, stream>>>(hA, W2, tbuf);
    k_conv<<<gNH, B, 0, stream>>>(tbuf, rowptr, csr_s, dinv, b2, hB);

    // conv3 reassociated through the pool: t3 = relu(hB) @ W3;
    // sums[g][c] = sum_s M[s][g] * t3[s][c]
    k_gemm<<<gG, B, 0, stream>>>(hB, W3, tbuf);
    k_mgemm<<<MG_BLOCKS, B, 0, stream>>>(tbuf, Mm, sums);

    // head (cnt via binary search on sorted batch)
    k_head2<<<1, B, 0, stream>>>(sums, batch, b3, Wpre, bpre, Wlin, blin, out);
}